// Round 6
// baseline (2262.521 us; speedup 1.0000x reference)
//
#include <hip/hip_runtime.h>
#include <hip/hip_bf16.h>

// R6 = BISECTION ROUND. R5's staging + conv1 + spatial-major bf16 s_act kept
// byte-identical; conv2 engine swapped to the R1-proven VALU path (lane =
// spatial, wave = 32-co group, W2 direct from global fp32, wave-uniform).
// If this passes at ~3.9e-3 the MFMA path is the bug; if it fails at ~1.2e-2
// the act infrastructure is.

#define IMG 2304
#define H1  1152
#define H2  576
#define C1c 64
#define C2c 128
#define TS  8               // conv2 outputs per block side (8x8 = 64 spatial)
#define NTB (H2/TS)         // 72
#define C1T 17              // conv1 tile side
#define C1S 289
#define APAD 72             // act row stride in bf16 (144 B)
#define IT  35              // image tile side

typedef __bf16 bf16x8 __attribute__((ext_vector_type(8)));
typedef float  f32x4  __attribute__((ext_vector_type(4)));

__global__ __launch_bounds__(256, 2) void hms2_fused(
    const int*    __restrict__ img,
    const float*  __restrict__ W1,
    const float*  __restrict__ b1,
    const float*  __restrict__ W2,
    const float*  __restrict__ b2,
    float*        __restrict__ out)
{
    __shared__ float  s_img[IT * IT * 3];
    __shared__ float  s_w1[27 * C1c];
    __shared__ __bf16 s_act[C1S * APAD];   // ~63 KB total -> 2 blocks/CU

    const int tid   = threadIdx.x;
    const int tileY = blockIdx.x / NTB;
    const int tileX = blockIdx.x % NTB;
    const int e0y = tileY * TS, e0x = tileX * TS;
    const int r0g = 2 * e0y,   q0g = 2 * e0x;
    const int iy0 = 4 * e0y,   ix0 = 4 * e0x;

    for (int i = tid; i < 27 * C1c; i += 256) s_w1[i] = W1[i];

    for (int i = tid; i < IT * IT * 3; i += 256) {
        int ch = i % 3;
        int p  = i / 3;
        int r  = p / IT, c = p % IT;
        int gy = iy0 + r, gx = ix0 + c;
        float v = 0.0f;
        if (gy < IMG && gx < IMG)
            v = (float)img[((size_t)gy * IMG + gx) * 3 + ch] * (1.0f / 255.0f);
        s_img[i] = v;
    }
    __syncthreads();

    // ---- conv1: BYTE-IDENTICAL to R5 ----
    for (int task = tid; task < 584; task += 256) {
        const int chunk = task & 7;
        const int co0   = chunk * 8;
        const int s0    = (task >> 3) * 4;

        int  pbase[4];
        bool valid[4];
        #pragma unroll
        for (int i = 0; i < 4; ++i) {
            int s  = s0 + i;
            bool in = (s < C1S);
            int r  = in ? (s / C1T) : 0;
            int c  = in ? (s - r * C1T) : 0;
            valid[i] = in && (r0g + r < H1) && (q0g + c < H1);
            pbase[i] = (2 * r * IT + 2 * c) * 3;
        }

        f32x4 av[4][2];
        #pragma unroll
        for (int i = 0; i < 4; ++i) { av[i][0] = (f32x4)0.f; av[i][1] = (f32x4)0.f; }

        #pragma unroll
        for (int t9 = 0; t9 < 9; ++t9) {
            const int ky = t9 / 3, kx = t9 % 3;
            const int toff = (ky * IT + kx) * 3;
            #pragma unroll
            for (int ci = 0; ci < 3; ++ci) {
                const f32x4* wp = (const f32x4*)&s_w1[(t9 * 3 + ci) * C1c + co0];
                f32x4 wa = wp[0], wb = wp[1];
                #pragma unroll
                for (int i = 0; i < 4; ++i) {
                    float x = s_img[pbase[i] + toff + ci];
                    av[i][0] += x * wa;
                    av[i][1] += x * wb;
                }
            }
        }

        const f32x4* b1v = (const f32x4*)(b1 + co0);
        f32x4 bb0 = b1v[0], bb1 = b1v[1];
        #pragma unroll
        for (int i = 0; i < 4; ++i) {
            int s = s0 + i;
            if (s < C1S) {
                bf16x8 o;
                #pragma unroll
                for (int j = 0; j < 4; ++j) {
                    float v0 = valid[i] ? fmaxf(av[i][0][j] + bb0[j], 0.f) : 0.f;
                    float v1 = valid[i] ? fmaxf(av[i][1][j] + bb1[j], 0.f) : 0.f;
                    o[j]     = (__bf16)v0;
                    o[j + 4] = (__bf16)v1;
                }
                *(bf16x8*)&s_act[s * APAD + chunk * 8] = o;
            }
        }
    }
    __syncthreads();

    // ---- conv2: R1-proven VALU engine on the NEW s_act layout ----
    // lane = spatial (8x8), wave wv -> co in [wv*32, wv*32+32).
    const int lane = tid & 63;
    const int h    = lane >> 3, w = lane & 7;
    const int wv   = __builtin_amdgcn_readfirstlane(tid >> 6);

    float acc[32];
    #pragma unroll
    for (int j = 0; j < 32; ++j) acc[j] = 0.0f;

    #pragma unroll
    for (int ky = 0; ky < 3; ++ky) {
        #pragma unroll
        for (int kx = 0; kx < 3; ++kx) {
            const int srow = (2 * h + ky) * C1T + (2 * w + kx);
            const int kbase = (ky * 3 + kx) * 64;
            for (int t = 0; t < 8; ++t) {                 // 8 ci-chunks of 8
                bf16x8 a8 = *(const bf16x8*)&s_act[srow * APAD + t * 8];
                #pragma unroll
                for (int e = 0; e < 8; ++e) {
                    float a = (float)a8[e];
                    const float* wq = &W2[(size_t)(kbase + t * 8 + e) * C2c + wv * 32];
                    #pragma unroll
                    for (int j = 0; j < 32; ++j)
                        acc[j] = fmaf(a, wq[j], acc[j]);   // wq wave-uniform -> scalar loads
                }
            }
        }
    }

    // ---- epilogue ----
    const int gy = e0y + h, gx = e0x + w;
    #pragma unroll
    for (int j = 0; j < 32; ++j) {
        int co = wv * 32 + j;
        float v = fmaxf(acc[j] + b2[co], 0.f);
        out[(size_t)co * (H2 * H2) + (size_t)gy * H2 + gx] = v;
    }
}

extern "C" void kernel_launch(void* const* d_in, const int* in_sizes, int n_in,
                              void* d_out, int out_size, void* d_ws, size_t ws_size,
                              hipStream_t stream) {
    const int*   img = (const int*)  d_in[0];
    const float* W1  = (const float*)d_in[1];
    const float* b1  = (const float*)d_in[2];
    const float* W2  = (const float*)d_in[3];
    const float* b2  = (const float*)d_in[4];
    float*       out = (float*)d_out;

    hms2_fused<<<dim3(NTB * NTB), dim3(256), 0, stream>>>(img, W1, b1, W2, b2, out);
}